// Round 1
// baseline (389.595 us; speedup 1.0000x reference)
//
#include <hip/hip_runtime.h>

// FFM forward, MI355X.
// Inputs (fp32 unless noted): dense[4096,13], sparse[4096,26] int32,
// w0[1], w[260013,1], v[260013,39,8].  Output: [4096,1] fp32.
//
// One block per batch row. 320 threads = 5 waves; thread e < 312 owns
// field_f element e = f*8+k. Gathers of v rows (1248 B contiguous) are
// coalesced across lanes; j-loop unrolled so 26 loads are in flight.

constexpr int V_DEPTH  = 10000;
constexpr int N_DENSE  = 13;
constexpr int N_SPARSE = 26;
constexpr int FIELD    = 39;   // 13 + 26
constexpr int K        = 8;
constexpr int FK       = FIELD * K;   // 312
constexpr int BLOCK    = 320;         // 5 waves
constexpr int NWAVES   = BLOCK / 64;

__global__ __launch_bounds__(BLOCK) void ffm_fwd_kernel(
    const float* __restrict__ dense,
    const int*   __restrict__ sparse,
    const float* __restrict__ w0,
    const float* __restrict__ w,
    const float* __restrict__ v,
    float*       __restrict__ out)
{
    const int b = blockIdx.x;
    const int t = threadIdx.x;

    __shared__ float s_dense[N_DENSE];
    __shared__ int   s_idx[N_SPARSE];
    __shared__ float s_wg[N_SPARSE];          // gathered w[idx]
    __shared__ float s_sq[NWAVES];            // per-wave sum of squares
    __shared__ float s_Sk[NWAVES][K];         // per-wave S_k partials

    if (t < N_DENSE) s_dense[t] = dense[b * N_DENSE + t];
    if (t < N_SPARSE) {
        const int id = sparse[b * N_SPARSE + t] + N_DENSE + t * V_DEPTH;
        s_idx[t] = id;
        s_wg[t]  = w[id];
    }
    __syncthreads();

    float acc = 0.0f;
    if (t < FK) {
        // dense @ v[0:13]  (16 KB, shared by all blocks -> L2 hot)
        #pragma unroll
        for (int d = 0; d < N_DENSE; ++d)
            acc += s_dense[d] * v[d * FK + t];
        // sum of 26 gathered v rows (coalesced: lanes read consecutive floats)
        #pragma unroll
        for (int j = 0; j < N_SPARSE; ++j)
            acc += v[(size_t)s_idx[j] * FK + t];
    }

    // --- reductions ---
    // sumsq over all 312 elements; S_k over elements with e % 8 == k.
    float sq = acc * acc;
    float sk = acc;
    #pragma unroll
    for (int off = 32; off >= 1; off >>= 1)
        sq += __shfl_xor(sq, off, 64);
    #pragma unroll
    for (int off = 32; off >= 8; off >>= 1)
        sk += __shfl_xor(sk, off, 64);          // lanes mod 8 congruent (64 % 8 == 0)

    const int wave = t >> 6;
    const int lane = t & 63;
    if (lane == 0) s_sq[wave] = sq;
    if (lane < K)  s_Sk[wave][lane] = sk;
    __syncthreads();

    if (t == 0) {
        float sumsq = 0.0f;
        #pragma unroll
        for (int wv = 0; wv < NWAVES; ++wv) sumsq += s_sq[wv];

        float ssum = 0.0f;
        #pragma unroll
        for (int k = 0; k < K; ++k) {
            float Sk = 0.0f;
            #pragma unroll
            for (int wv = 0; wv < NWAVES; ++wv) Sk += s_Sk[wv][k];
            ssum += Sk * Sk;
        }

        float linear = w0[0];
        #pragma unroll
        for (int j = 0; j < N_SPARSE; ++j) linear += s_wg[j];
        #pragma unroll
        for (int d = 0; d < N_DENSE; ++d)  linear += s_dense[d] * w[d];

        out[b] = linear + 0.5f * (ssum - sumsq);
    }
}

extern "C" void kernel_launch(void* const* d_in, const int* in_sizes, int n_in,
                              void* d_out, int out_size, void* d_ws, size_t ws_size,
                              hipStream_t stream) {
    const float* dense  = (const float*)d_in[0];
    const int*   sparse = (const int*)  d_in[1];
    const float* w0     = (const float*)d_in[2];
    const float* w      = (const float*)d_in[3];
    const float* v      = (const float*)d_in[4];
    float* out = (float*)d_out;

    const int batch = out_size;   // 4096
    ffm_fwd_kernel<<<batch, BLOCK, 0, stream>>>(dense, sparse, w0, w, v, out);
}